// Round 6
// baseline (209.674 us; speedup 1.0000x reference)
//
#include <hip/hip_runtime.h>
#include <stdint.h>

using short8  = __attribute__((ext_vector_type(8))) short;   // 8 bf16 = 4 VGPRs
using f32x4   = __attribute__((ext_vector_type(4))) float;
using float4v = __attribute__((ext_vector_type(4))) float;
using u16x4   = __attribute__((ext_vector_type(4))) unsigned short;

__device__ __forceinline__ unsigned short f2b(float f) {
    union { float f; unsigned int i; } v; v.f = f;
    unsigned int i = v.i;
    unsigned int r = (i + 0x7fffu + ((i >> 16) & 1u)) >> 16;   // RNE
    return (unsigned short)r;
}
__device__ __forceinline__ unsigned short f2bt(float f) {      // truncate (1 VALU)
    union { float f; unsigned int i; } v; v.f = f;
    return (unsigned short)(v.i >> 16);
}
__device__ __forceinline__ short8 ld8(const unsigned short* p) {
    return *reinterpret_cast<const short8*>(p);
}
__device__ __forceinline__ void st8(unsigned short* p, short8 v) {
    *reinterpret_cast<short8*>(p) = v;
}
__device__ __forceinline__ f32x4 mfma16(short8 a, short8 b, f32x4 c) {
    return __builtin_amdgcn_mfma_f32_16x16x32_bf16(a, b, c, 0, 0, 0);
}
__device__ __forceinline__ void stC(float* p, float v)          { *p = v; }
__device__ __forceinline__ void stC(unsigned short* p, float v) { *p = f2b(v); }

// ---------------------------------------------------------------------------
// Stage 0: x (fp32) -> xbf (bf16).  4M elements, 4/thread.
// ---------------------------------------------------------------------------
__global__ __launch_bounds__(256) void cvt_kernel(const float* __restrict__ in,
                                                  unsigned short* __restrict__ out)
{
    int i = blockIdx.x * 256 + threadIdx.x;
    float4v v = reinterpret_cast<const float4v*>(in)[i];
    u16x4 o;
#pragma unroll
    for (int j = 0; j < 4; ++j) o[j] = f2b(v[j]);
    reinterpret_cast<u16x4*>(out)[i] = o;
}

// ---------------------------------------------------------------------------
// Stage 1: style[map][b][i] = dot(s[b,:], aff_w[i,:]) + aff_b[i]   (fp32)
// ---------------------------------------------------------------------------
__global__ __launch_bounds__(256) void style_kernel(
    const float* __restrict__ s,
    const float* __restrict__ k_aff_w, const float* __restrict__ k_aff_b,
    const float* __restrict__ o_aff_w, const float* __restrict__ o_aff_b,
    float* __restrict__ style)
{
    int wid  = blockIdx.x * 4 + (threadIdx.x >> 6);
    int lane = threadIdx.x & 63;
    int map  = wid >> 12;
    int rem  = wid & 4095;
    int b    = rem >> 9;
    int i    = rem & 511;
    const float* aw = map ? o_aff_w : k_aff_w;
    const float* ab = map ? o_aff_b : k_aff_b;
    const float* sp = s  + b * 512 + lane * 8;
    const float* wp = aw + i * 512 + lane * 8;
    float acc = 0.f;
#pragma unroll
    for (int j = 0; j < 8; ++j) acc += sp[j] * wp[j];
#pragma unroll
    for (int off = 1; off < 64; off <<= 1) acc += __shfl_xor(acc, off, 64);
    if (lane == 0) style[(map * 8 + b) * 512 + i] = acc + ab[i];
}

// ---------------------------------------------------------------------------
// Stage 2: wmod[map][b][o][i] = bf16( weight[o][i]*style[map][b][i] * demod )
// ---------------------------------------------------------------------------
__global__ __launch_bounds__(256) void modw_kernel(
    const float* __restrict__ k_weight,
    const float* __restrict__ o_weight,
    const float* __restrict__ style,
    unsigned short* __restrict__ wmod)
{
    int wid  = blockIdx.x * 4 + (threadIdx.x >> 6);
    int lane = threadIdx.x & 63;
    int map  = wid >> 12;
    int rem  = wid & 4095;
    int b    = rem >> 9;
    int o    = rem & 511;
    const float* wrow = (map ? o_weight : k_weight) + o * 512 + lane * 8;
    const float* st   = style + (map * 8 + b) * 512 + lane * 8;
    float w[8]; float ss = 0.f;
#pragma unroll
    for (int j = 0; j < 8; ++j) { w[j] = wrow[j] * st[j]; ss += w[j] * w[j]; }
#pragma unroll
    for (int off = 1; off < 64; off <<= 1) ss += __shfl_xor(ss, off, 64);
    float demod = rsqrtf(ss + 1e-8f);
    short8 ov;
#pragma unroll
    for (int j = 0; j < 8; ++j) ov[j] = (short)f2b(w[j] * demod);
    unsigned short* dst = wmod + (((size_t)map * 8 + b) * 512 + o) * 512 + lane * 8;
    *reinterpret_cast<short8*>(dst) = ov;
}

// ---------------------------------------------------------------------------
// Stage 3/5 (R6): batched GEMM, LDS-staged + double-buffered.
// C[b][m][n] = sum_k A[b][m][k] * Bt[b][n][k];  M=1024, N=512, K=512, B=8.
// Block tile 128x64, BK=32, 4 waves (2x2), wave tile 64x32 (4x2 MFMA tiles).
// WVT: fused epilogue writes VT[b*8+nt][d][token] (the old transpose kernel)
// via an in-LDS transpose reusing the staging smem (N-tile width 64 == head).
// grid = 8*8*8 = 512 blocks.
// ---------------------------------------------------------------------------
template <typename CT, bool WVT>
__global__ __launch_bounds__(256) void gemm_bt_lds_kernel(
    const unsigned short* __restrict__ A,
    const unsigned short* __restrict__ Bt,
    CT* __restrict__ C,
    unsigned short* __restrict__ VT)
{
    constexpr int KP = 40;
    constexpr int TP = 136;   // transpose row pad: 272 B = 17*16 (16B-aligned rows)
    __shared__ __align__(16) unsigned short smem[2 * 128 * KP + 2 * 64 * KP];
    typedef unsigned short APlane[128][KP];
    typedef unsigned short BPlane[64][KP];
    APlane* As = reinterpret_cast<APlane*>(smem);
    BPlane* Bs = reinterpret_cast<BPlane*>(smem + 2 * 128 * KP);

    int blk = blockIdx.x;
    int nt = blk & 7;
    int mt = (blk >> 3) & 7;
    int b  = blk >> 6;
    int tid  = threadIdx.x;
    int w    = tid >> 6;
    int lane = tid & 63;
    int quad = lane >> 4;
    int r    = lane & 15;
    int wm   = w >> 1;          // 0..1 (M half)
    int wn   = w & 1;           // 0..1 (N half)

    const unsigned short* Ab = A  + ((size_t)b * 1024 + mt * 128) * 512;
    const unsigned short* Bb = Bt + ((size_t)b * 512  + nt * 64 ) * 512;

    int srow = lane >> 2;          // 0..15
    int scol = (lane & 3) * 8;     // 0,8,16,24
    const unsigned short* ga0 = Ab + (size_t)(w * 32 + srow) * 512 + scol;
    const unsigned short* ga1 = ga0 + (size_t)16 * 512;
    const unsigned short* gb0 = Bb + (size_t)(w * 16 + srow) * 512 + scol;

    f32x4 acc[4][2];
#pragma unroll
    for (int i = 0; i < 4; ++i)
#pragma unroll
        for (int j = 0; j < 2; ++j) acc[i][j] = f32x4{0.f, 0.f, 0.f, 0.f};

    {
        short8 pa0 = ld8(ga0), pa1 = ld8(ga1), pb0 = ld8(gb0);
        st8(&As[0][w * 32 + srow][scol],      pa0);
        st8(&As[0][w * 32 + 16 + srow][scol], pa1);
        st8(&Bs[0][w * 16 + srow][scol],      pb0);
    }
    __syncthreads();

    for (int ks = 0; ks < 16; ++ks) {
        int s = ks & 1;
        short8 pa0, pa1, pb0;
        if (ks < 15) {
            int ko = (ks + 1) * 32;
            pa0 = ld8(ga0 + ko);
            pa1 = ld8(ga1 + ko);
            pb0 = ld8(gb0 + ko);
        }
        short8 af[4], bf[2];
#pragma unroll
        for (int i = 0; i < 4; ++i)
            af[i] = ld8(&As[s][wm * 64 + i * 16 + r][quad * 8]);
#pragma unroll
        for (int j = 0; j < 2; ++j)
            bf[j] = ld8(&Bs[s][wn * 32 + j * 16 + r][quad * 8]);
#pragma unroll
        for (int i = 0; i < 4; ++i)
#pragma unroll
            for (int j = 0; j < 2; ++j)
                acc[i][j] = mfma16(af[i], bf[j], acc[i][j]);
        if (ks < 15) {
            int ns = s ^ 1;
            st8(&As[ns][w * 32 + srow][scol],      pa0);
            st8(&As[ns][w * 32 + 16 + srow][scol], pa1);
            st8(&Bs[ns][w * 16 + srow][scol],      pb0);
        }
        __syncthreads();
    }

    CT* Cb = C + (size_t)b * 1024 * 512;
    unsigned short (*Tt)[TP] = reinterpret_cast<unsigned short (*)[TP]>(smem);
#pragma unroll
    for (int i = 0; i < 4; ++i) {
#pragma unroll
        for (int rr = 0; rr < 4; ++rr) {
            int row = mt * 128 + wm * 64 + i * 16 + quad * 4 + rr;
#pragma unroll
            for (int j = 0; j < 2; ++j) {
                int col = nt * 64 + wn * 32 + j * 16 + r;
                stC(Cb + (size_t)row * 512 + col, acc[i][j][rr]);
            }
        }
        if (WVT) {
            // pack rr-pairs -> LDS transposed tile Tt[d][token]
#pragma unroll
            for (int j = 0; j < 2; ++j) {
                int d = wn * 32 + j * 16 + r;
#pragma unroll
                for (int rh = 0; rh < 2; ++rh) {
                    int row = wm * 64 + i * 16 + quad * 4 + rh * 2;
                    unsigned int pv = (unsigned int)f2b(acc[i][j][rh * 2]) |
                                      ((unsigned int)f2b(acc[i][j][rh * 2 + 1]) << 16);
                    *reinterpret_cast<unsigned int*>(&Tt[d][row]) = pv;
                }
            }
        }
    }
    if (WVT) {
        __syncthreads();
        int d  = tid >> 2;          // 0..63
        int cc = tid & 3;           // token chunk of 32
        const unsigned short* src = &Tt[d][cc * 32];
        unsigned short* dst = VT + ((size_t)(b * 8 + nt) * 64 + d) * 1024 + mt * 128 + cc * 32;
        short8 t0 = ld8(src), t1 = ld8(src + 8), t2 = ld8(src + 16), t3 = ld8(src + 24);
        st8(dst,      t0);
        st8(dst + 8,  t1);
        st8(dst + 16, t2);
        st8(dst + 24, t3);
    }
}

// ---------------------------------------------------------------------------
// Stage 4: flash attention (R6): 32 q-rows/wave (two 16-row B-frag groups);
// K/V frags read from LDS once, used by both groups (~1.8x fewer LDS reads
// per unit work). PAD=68 (stride 34 dwords === 2 mod 4): conflict-free per
// quarter-wave for all frag reads/writes. Static-max softmax (R5). No
// intra-iter barriers except the staging one.
// grid = 512 blocks x 256 (8 blocks per (b,h), XCD swizzle blk&63).
// ---------------------------------------------------------------------------
__global__ __launch_bounds__(256) void attn_kernel(
    const unsigned short* __restrict__ kqv,
    const unsigned short* __restrict__ vt,
    unsigned short* __restrict__ attn_out)
{
    constexpr int PAD = 68;
    int blk = blockIdx.x;
    int bh = blk & 63;            // XCD-locality
    int qt = blk >> 6;            // 0..7
    int b  = bh >> 3, h = bh & 7;
    int tid  = threadIdx.x;
    int wv   = tid >> 6;
    int lane = tid & 63;
    int quad = lane >> 4;
    int r    = lane & 15;

    __shared__ __align__(16) unsigned short klds[2][64][PAD];   // 17.0 KB
    __shared__ __align__(16) unsigned short vlds[2][64][PAD];   // 17.0 KB
    __shared__ __align__(16) unsigned short plds[4][2][16][PAD];// 17.0 KB
    unsigned short (*myp)[16][PAD] = plds[wv];

    const unsigned short* Mb = kqv + (size_t)b * 1024 * 512;
    int q0 = qt * 128 + wv * 32;

    short8 bq[2][2];
#pragma unroll
    for (int g = 0; g < 2; ++g) {
        const unsigned short* qp = Mb + (size_t)(q0 + g * 16 + r) * 512 + h * 64 + quad * 8;
        bq[g][0] = ld8(qp);
        bq[g][1] = ld8(qp + 32);
    }

    short8 ones;
#pragma unroll
    for (int j = 0; j < 8; ++j) ones[j] = (short)0x3F80;   // bf16 1.0

    f32x4 o[2][4], lacc[2];
#pragma unroll
    for (int g = 0; g < 2; ++g) {
        lacc[g] = f32x4{0.f, 0.f, 0.f, 0.f};
#pragma unroll
        for (int j = 0; j < 4; ++j) o[g][j] = f32x4{0.f, 0.f, 0.f, 0.f};
    }

    int srow0 = tid >> 3;          // 0..31
    int srow1 = srow0 + 32;
    int scol  = (tid & 7) * 8;
    const unsigned short* Kg = Mb + h * 64;
    const unsigned short* Vg = vt + (size_t)bh * 64 * 1024;

    {
        short8 k0v = ld8(Kg + (size_t)srow0 * 512 + scol);
        short8 k1v = ld8(Kg + (size_t)srow1 * 512 + scol);
        short8 v0v = ld8(Vg + (size_t)srow0 * 1024 + scol);
        short8 v1v = ld8(Vg + (size_t)srow1 * 1024 + scol);
        st8(&klds[0][srow0][scol], k0v);
        st8(&klds[0][srow1][scol], k1v);
        st8(&vlds[0][srow0][scol], v0v);
        st8(&vlds[0][srow1][scol], v1v);
    }
    __syncthreads();

    const float c  = 0.18033688011112042f;   // (1/8) * log2(e)
    const float CM = 28.853900817779268f;    // 20 * log2(e)

    for (int it = 0; it < 16; ++it) {
        int s = it & 1;
        short8 pk0, pk1, pv0, pv1;
        if (it < 15) {
            int k0n = (it + 1) * 64;
            pk0 = ld8(Kg + (size_t)(k0n + srow0) * 512 + scol);
            pk1 = ld8(Kg + (size_t)(k0n + srow1) * 512 + scol);
            pv0 = ld8(Vg + (size_t)srow0 * 1024 + k0n + scol);
            pv1 = ld8(Vg + (size_t)srow1 * 1024 + k0n + scol);
        }
        // ---- S^T: K frags read ONCE, used by both q-groups
        f32x4 st_[2][4];
#pragma unroll
        for (int t = 0; t < 4; ++t) {
            short8 ka = ld8(&klds[s][t * 16 + r][quad * 8]);
            short8 kb = ld8(&klds[s][t * 16 + r][32 + quad * 8]);
#pragma unroll
            for (int g = 0; g < 2; ++g) {
                f32x4 sacc = {0.f, 0.f, 0.f, 0.f};
                sacc = mfma16(ka, bq[g][0], sacc);
                sacc = mfma16(kb, bq[g][1], sacc);
                st_[g][t] = sacc;
            }
        }
        // ---- P = exp2(s*c - CM) -> wave-private LDS (A-layout rows)
#pragma unroll
        for (int g = 0; g < 2; ++g)
#pragma unroll
            for (int t = 0; t < 4; ++t) {
                u16x4 pb;
#pragma unroll
                for (int rr = 0; rr < 4; ++rr)
                    pb[rr] = f2bt(exp2f(st_[g][t][rr] * c - CM));
                *reinterpret_cast<u16x4*>(&myp[g][r][t * 16 + quad * 4]) = pb;
            }
        short8 ap[2][2];
#pragma unroll
        for (int g = 0; g < 2; ++g) {
            ap[g][0] = ld8(&myp[g][r][quad * 8]);
            ap[g][1] = ld8(&myp[g][r][32 + quad * 8]);
        }
        // ---- PV: V frags read ONCE, used by both q-groups
#pragma unroll
        for (int t = 0; t < 4; ++t) {
            short8 va = ld8(&vlds[s][t * 16 + r][quad * 8]);
            short8 vb = ld8(&vlds[s][t * 16 + r][32 + quad * 8]);
#pragma unroll
            for (int g = 0; g < 2; ++g) {
                o[g][t] = mfma16(ap[g][0], va, o[g][t]);
                o[g][t] = mfma16(ap[g][1], vb, o[g][t]);
            }
        }
#pragma unroll
        for (int g = 0; g < 2; ++g) {
            lacc[g] = mfma16(ap[g][0], ones, lacc[g]);
            lacc[g] = mfma16(ap[g][1], ones, lacc[g]);
        }
        if (it < 15) {
            int ns = s ^ 1;
            st8(&klds[ns][srow0][scol], pk0);
            st8(&klds[ns][srow1][scol], pk1);
            st8(&vlds[ns][srow0][scol], pv0);
            st8(&vlds[ns][srow1][scol], pv1);
        }
        __syncthreads();
    }

    unsigned short* ob = attn_out + (size_t)b * 1024 * 512 + (size_t)h * 64;
#pragma unroll
    for (int g = 0; g < 2; ++g)
#pragma unroll
        for (int rr = 0; rr < 4; ++rr) {
            float inv = 1.0f / lacc[g][rr];
            int n = q0 + g * 16 + quad * 4 + rr;
            unsigned short* orow = ob + (size_t)n * 512 + r;
            orow[0]  = f2b(o[g][0][rr] * inv);
            orow[16] = f2b(o[g][1][rr] * inv);
            orow[32] = f2b(o[g][2][rr] * inv);
            orow[48] = f2b(o[g][3][rr] * inv);
        }
}

// ---------------------------------------------------------------------------
extern "C" void kernel_launch(void* const* d_in, const int* in_sizes, int n_in,
                              void* d_out, int out_size, void* d_ws, size_t ws_size,
                              hipStream_t stream)
{
    const float* x        = (const float*)d_in[0];
    const float* s        = (const float*)d_in[1];
    const float* k_weight = (const float*)d_in[2];
    const float* k_aff_w  = (const float*)d_in[3];
    const float* k_aff_b  = (const float*)d_in[4];
    const float* o_weight = (const float*)d_in[5];
    const float* o_aff_w  = (const float*)d_in[6];
    const float* o_aff_b  = (const float*)d_in[7];
    float* out = (float*)d_out;

    char* ws = (char*)d_ws;
    float* style          = (float*)ws;                                   // 32 KB
    unsigned short* wmod  = (unsigned short*)(ws + 32 * 1024);            // 8 MB (both maps)
    unsigned short* xbf   = wmod + (size_t)2 * 8 * 512 * 512;             // 8 MB (reused as attn)
    unsigned short* kqv   = xbf  + (size_t)8 * 1024 * 512;                // 8 MB
    unsigned short* vt    = kqv  + (size_t)8 * 1024 * 512;                // 8 MB
    unsigned short* attn  = xbf;   // x is dead after GEMM1 -> alias

    cvt_kernel<<<4096, 256, 0, stream>>>(x, xbf);
    style_kernel<<<2048, 256, 0, stream>>>(s, k_aff_w, k_aff_b, o_aff_w, o_aff_b, style);
    modw_kernel<<<2048, 256, 0, stream>>>(k_weight, o_weight, style, wmod);
    gemm_bt_lds_kernel<unsigned short, true><<<512, 256, 0, stream>>>(xbf, wmod, kqv, vt);
    attn_kernel<<<512, 256, 0, stream>>>(kqv, vt, attn);
    gemm_bt_lds_kernel<float, false><<<512, 256, 0, stream>>>(attn, wmod + (size_t)8 * 512 * 512, out, nullptr);
}